// Round 10
// baseline (305.463 us; speedup 1.0000x reference)
//
#include <hip/hip_runtime.h>
#include <stdint.h>

// Problem constants
#define ZSIZE   8388608      // 32*256*32*32
#define NPIX    32768        // 32*32*32
#define IDX_OFF ZSIZE        // idx output offset (floats) in d_out
#define LOSS_OFF (ZSIZE + NPIX)
#define ET_OFF  1024         // Et fp32 [256][1024] scratch (for kse)
#define E1_OFF  263168       // e1s swizzled bf16 (131072 floats = 512 KB)
#define ZT_OFF  394240       // zt bf16 [32][1024][256] (4194304 floats)
#define SZ_OFF  4588544      // sz fp32 [32][1024] (32768 floats), after zt
#define CAP     24           // candidate slots per pixel
#define WWIN    6.0e-3f      // window >= 2*eps_bound (eps<=2.4e-3 rigorous)

using v8s = __attribute__((ext_vector_type(8))) short;   // 8 bf16 (4 VGPR)
using v4f = __attribute__((ext_vector_type(4))) float;   // MFMA acc

__device__ __forceinline__ unsigned short bf16rne(float f) {
  unsigned u = __float_as_uint(f);
  return (unsigned short)((u + 0x7FFFu + ((u >> 16) & 1u)) >> 16);
}

// ---------------------------------------------------------------------------
// ktr: transpose embedding E[1024][256] -> Et[256][1024] (feeds kse only)
// ---------------------------------------------------------------------------
__global__ __launch_bounds__(256) void ktr(const float* __restrict__ E,
                                           float* __restrict__ out) {
  __shared__ float tile[64][65];
  const int k0 = blockIdx.x * 64;
  const int c0 = blockIdx.y * 64;
  const int t = threadIdx.x;
  #pragma unroll
  for (int i = 0; i < 4; i++) {
    int f = t + 256 * i;
    int r = f >> 4, q = f & 15;
    float4 e = *(const float4*)(E + (k0 + r) * 256 + c0 + 4 * q);
    tile[r][4 * q + 0] = e.x; tile[r][4 * q + 1] = e.y;
    tile[r][4 * q + 2] = e.z; tile[r][4 * q + 3] = e.w;
  }
  __syncthreads();
  #pragma unroll
  for (int i = 0; i < 4; i++) {
    int f = t + 256 * i;
    int cr = f >> 4, kq = f & 15;
    float4 o;
    o.x = tile[4 * kq + 0][cr];
    o.y = tile[4 * kq + 1][cr];
    o.z = tile[4 * kq + 2][cr];
    o.w = tile[4 * kq + 3][cr];
    *(float4*)(out + ET_OFF + (c0 + cr) * 1024 + k0 + 4 * kq) = o;
  }
}

// ---------------------------------------------------------------------------
// kse: se[k] = ascending-c sequential fp32 chain of E[k][c]^2 (bit-faithful)
// ---------------------------------------------------------------------------
__global__ __launch_bounds__(256) void kse(float* __restrict__ out) {
  const int k = blockIdx.x * 256 + threadIdx.x;
  const float* Et = out + ET_OFF;
  float acc = 0.0f;
  #pragma unroll 8
  for (int c = 0; c < 256; c++) {
    float v = Et[c * 1024 + k];
    acc = __fadd_rn(acc, __fmul_rn(v, v));
  }
  out[k] = acc;
}

// ---------------------------------------------------------------------------
// kes: swizzled bf16 embedding in MFMA B-fragment order.
// e1s[tile][s][lane] (16B chunks): tile = code0/16 (0..63), s = 0..7,
// lane = 0..63 (r=lane&15, h=(lane>>4)&3).
// chunk = bf16(E[16*tile + r][8*h + 32*s + 0..7]).
// A wave's B-load for (tile,s) is 64 lanes x 16B = 1KB contiguous.
// ---------------------------------------------------------------------------
__global__ __launch_bounds__(256) void kes(const float* __restrict__ E,
                                           float* __restrict__ out) {
  unsigned short* e1s = (unsigned short*)(out + E1_OFF);
  const int tile = blockIdx.x;       // 0..63
  const int t = threadIdx.x;
  #pragma unroll
  for (int i = 0; i < 2; i++) {
    int chunk = t + 256 * i;         // 0..511
    int s = chunk >> 6, lane = chunk & 63;
    int r = lane & 15, h = (lane >> 4) & 3;
    const float* src = E + (16 * tile + r) * 256 + 8 * h + 32 * s;
    unsigned short o[8];
    #pragma unroll
    for (int j = 0; j < 8; j++) o[j] = bf16rne(src[j]);
    *(uint4*)(e1s + (size_t)tile * 4096 + (size_t)chunk * 8) = *(const uint4*)o;
  }
}

// ---------------------------------------------------------------------------
// kzt: zt[b][n][c] = bf16_rne(zz[c][n]), n = w0*256 + m.  R10: also emits
// szg[b][n] = exact ascending-c fp32 chain of zz[c][n]^2 from the staged
// fp32 tile (bit-identical to the reference; removes kmain's serial,
// cold-global sz prologue — the R9 regression).
// ---------------------------------------------------------------------------
__global__ __launch_bounds__(256) void kzt(const float* __restrict__ z,
                                           float* __restrict__ out) {
  __shared__ float tile[16][1028];   // 16 z-rows x 1024, pad 1028
  unsigned short* zt = (unsigned short*)(out + ZT_OFF);
  float* szg = out + SZ_OFF;
  const int mg = blockIdx.x;         // 0..15 (16-row group)
  const int b  = blockIdx.y;         // 0..31
  const int t = threadIdx.x;
  #pragma unroll
  for (int i = 0; i < 16; i++) {     // row m=i, q=t: coalesced float4 loads
    float4 v = *(const float4*)(z + (size_t)b * 262144 + (size_t)(mg * 16 + i) * 1024 + 4 * t);
    *(float4*)&tile[i][4 * t] = v;
  }
  __syncthreads();
  const int m = t & 15, w0 = (t >> 4) & 3;   // R = t&63 spans (m,w0)
  const int n = w0 * 256 + mg * 16 + m;
  #pragma unroll
  for (int i = 0; i < 8; i++) {
    int g = 4 * i + (t >> 6);        // 0..31: 8-channel group
    int c0 = 8 * g;
    unsigned short o[8];
    #pragma unroll
    for (int j = 0; j < 8; j++)
      o[j] = bf16rne(tile[m][4 * (c0 + j) + w0]);
    *(uint4*)(zt + ((size_t)(b * 1024 + n)) * 256 + c0) = *(const uint4*)o;
  }
  // ---- sz: exact sequential chain per pixel (64 threads; 2-way banks) ----
  if (t < 64) {
    const int ms = t >> 2, ws = t & 3;
    float a = 0.0f;
    #pragma unroll 8
    for (int c = 0; c < 256; c++) {
      float v = tile[ms][4 * c + ws];
      a = __fadd_rn(a, __fmul_rn(v, v));
    }
    szg[b * 1024 + ws * 256 + mg * 16 + ms] = a;
  }
}

// ---------------------------------------------------------------------------
// kmain: MFMA approximate distances + provably-sound exact rescreen.
// R10 change: R9's occupancy was GRID-limited (512 blocks x 4 waves = 8
// waves/CU = 22%), not resource-limited — freeing LDS did nothing, and
// dropping VsT made the serial sz prologue cold-global (the 120->172
// regression).  Fix 1: T-SPLIT — 512-thread blocks, 8 waves; waves 0-3
// take T-pair {0,1}, waves 4-7 take {2,3} (Tp = t>>8 replaces the Tp
// loop).  Per-wave work halves, total waves double -> 16 waves/CU.
// e1s traffic unchanged; pixel sets per half disjoint.  Fix 2: sz comes
// precomputed from kzt (64-float L2 read).  K-loop body = R5/R9's proven
// no-spill form, untouched.  Canaries: VGPR ~76-100 (NOT 128), WRITE ~128KB.
// ---------------------------------------------------------------------------
__global__ __launch_bounds__(512, 2) void kmain(const float* __restrict__ z,
                                                const float* __restrict__ E,
                                                float* __restrict__ out) {
  __shared__ __attribute__((aligned(16))) float szs[64];
  __shared__ __attribute__((aligned(16))) float dmins[64];
  __shared__ int   candK[64 * CAP];
  __shared__ float candD[64 * CAP];
  __shared__ int   cnt[64];

  const int t = threadIdx.x;           // 0..511
  const int ccg = blockIdx.x, b = blockIdx.y;
  const int cc0 = ccg * 16;
  const int lane = t & 63;
  const int w = (t >> 6) & 3;          // code-tile phase (mod 4)
  const int Tp = t >> 8;               // 0: T={0,1}; 1: T={2,3}
  const int r = t & 15, h = (t >> 4) & 3;
  const int w16r = w * 16 + r;
  const float* zb = z + (size_t)b * 262144;
  const float* se_g = out;
  const unsigned short* e1s = (const unsigned short*)(out + E1_OFF);
  const unsigned short* zt = (const unsigned short*)(out + ZT_OFF);
  const float* szg = out + SZ_OFF;

  if (t < 64) {
    cnt[t] = 0; dmins[t] = 3.4e38f;
    // local px p = 4*row + w0  <->  n = w0*256 + cc0 + row
    szs[t] = szg[b * 1024 + (t & 3) * 256 + cc0 + (t >> 2)];
  }
  __syncthreads();

  // ---- per-lane se for its 16 codes ----
  float se16r[16];
  #pragma unroll
  for (int ti = 0; ti < 16; ti++) se16r[ti] = se_g[ti * 64 + w16r];

  const int T0 = 2 * Tp, T1 = T0 + 1;

  // ---- A-frags for this half's T-pair ----
  v8s A0[8], A1[8];
  {
    const unsigned short* a0p =
        zt + ((size_t)(b * 1024 + T0 * 256 + cc0 + r)) * 256 + 8 * h;
    const unsigned short* a1p = a0p + 256 * 256;   // T1 = T0+1
    #pragma unroll
    for (int s = 0; s < 8; s++) {
      A0[s] = *(const v8s*)(a0p + 32 * s);
      A1[s] = *(const v8s*)(a1p + 32 * s);
    }
  }
  float sz0[4], sz1[4];
  #pragma unroll
  for (int reg = 0; reg < 4; reg++) {
    sz0[reg] = szs[16 * h + 4 * reg + T0];
    sz1[reg] = szs[16 * h + 4 * reg + T1];
  }

  // ======== phase 1: min scan (branchless) ========
  {
    float b0[4], b1[4];
    #pragma unroll
    for (int reg = 0; reg < 4; reg++) { b0[reg] = 3.4e38f; b1[reg] = 3.4e38f; }

    #pragma unroll 4
    for (int ti = 0; ti < 16; ti++) {
      const unsigned short* bb = e1s + (size_t)(4 * ti + w) * 4096 + (size_t)lane * 8;
      v4f acc0 = (v4f){0.f, 0.f, 0.f, 0.f};
      v4f acc1 = (v4f){0.f, 0.f, 0.f, 0.f};
      #pragma unroll
      for (int s = 0; s < 8; s++) {
        v8s B_ = *(const v8s*)(bb + 512 * s);
        acc0 = __builtin_amdgcn_mfma_f32_16x16x32_bf16(A0[s], B_, acc0, 0, 0, 0);
        acc1 = __builtin_amdgcn_mfma_f32_16x16x32_bf16(A1[s], B_, acc1, 0, 0, 0);
      }
      float se_l = se16r[ti];
      #pragma unroll
      for (int reg = 0; reg < 4; reg++) {
        b0[reg] = fminf(b0[reg], (se_l + sz0[reg]) - 2.0f * acc0[reg]);
        b1[reg] = fminf(b1[reg], (se_l + sz1[reg]) - 2.0f * acc1[reg]);
      }
    }
    #pragma unroll
    for (int reg = 0; reg < 4; reg++) {
      atomicMin((int*)&dmins[16 * h + 4 * reg + T0], __float_as_int(b0[reg]));
      atomicMin((int*)&dmins[16 * h + 4 * reg + T1], __float_as_int(b1[reg]));
    }
  }
  __syncthreads();   // dmins exact-final

  // ======== phase 2: recompute dd, append dd <= dmin + W ========
  {
    float th0[4], th1[4];
    #pragma unroll
    for (int reg = 0; reg < 4; reg++) {
      th0[reg] = dmins[16 * h + 4 * reg + T0] + WWIN;
      th1[reg] = dmins[16 * h + 4 * reg + T1] + WWIN;
    }

    #pragma unroll 4
    for (int ti = 0; ti < 16; ti++) {
      const unsigned short* bb = e1s + (size_t)(4 * ti + w) * 4096 + (size_t)lane * 8;
      v4f acc0 = (v4f){0.f, 0.f, 0.f, 0.f};
      v4f acc1 = (v4f){0.f, 0.f, 0.f, 0.f};
      #pragma unroll
      for (int s = 0; s < 8; s++) {
        v8s B_ = *(const v8s*)(bb + 512 * s);
        acc0 = __builtin_amdgcn_mfma_f32_16x16x32_bf16(A0[s], B_, acc0, 0, 0, 0);
        acc1 = __builtin_amdgcn_mfma_f32_16x16x32_bf16(A1[s], B_, acc1, 0, 0, 0);
      }
      float se_l = se16r[ti];
      const int kl = ti * 64 + w16r;
      #pragma unroll
      for (int reg = 0; reg < 4; reg++) {
        float dd0 = (se_l + sz0[reg]) - 2.0f * acc0[reg];
        if (dd0 <= th0[reg]) {
          int p = 16 * h + 4 * reg + T0;
          int o = atomicAdd(&cnt[p], 1);
          if (o < CAP) { candK[p * CAP + o] = kl; candD[p * CAP + o] = dd0; }
        }
        float dd1 = (se_l + sz1[reg]) - 2.0f * acc1[reg];
        if (dd1 <= th1[reg]) {
          int p = 16 * h + 4 * reg + T1;
          int o = atomicAdd(&cnt[p], 1);
          if (o < CAP) { candK[p * CAP + o] = kl; candD[p * CAP + o] = dd1; }
        }
      }
    }
  }
  __syncthreads();   // all appends visible

  // ---- exact rescreen: bit-identical fp32 chain; z read from global ----
  for (int i = t; i < 64 * CAP; i += 512) {
    int p = i / CAP, slot = i - p * CAP;
    int cn = cnt[p];
    if (cn > CAP || slot >= cn) continue;     // overflow px -> fallback
    int k = candK[i];
    const float* er = E + (size_t)k * 256;
    const float* zp = zb + (cc0 + (p >> 2)) * 1024 + (p & 3);
    float dot = 0.0f;
    #pragma unroll 8
    for (int c = 0; c < 256; c++)
      dot = __fmaf_rn(zp[4 * c], er[c], dot);
    candD[i] = __fsub_rn(__fadd_rn(se_g[k], szs[p]), __fmul_rn(2.0f, dot));
  }
  __syncthreads();

  // ---- winners: lexicographic (d,k) min == first-index argmin ----
  if (t < 64) {
    int p = t, cn = cnt[p];
    if (cn <= CAP) {
      float bd = 3.4e38f; int bi = 0x7FFFFFFF;
      for (int s2 = 0; s2 < cn; s2++) {
        float d2 = candD[p * CAP + s2]; int k2 = candK[p * CAP + s2];
        if (d2 < bd || (d2 == bd && k2 < bi)) { bd = d2; bi = k2; }
      }
      int rr = p >> 2, w0 = p & 3;
      out[IDX_OFF + b * 1024 + (w0 * 256 + cc0 + rr)] = (float)bi;
    }
  }

  // ---- fallback: overflowed px -> exact full scan by one wave (dead code
  // in practice; Tp==0 half only to avoid duplicate scans) ----
  for (int p = 0; p < 64; p++) {
    if (cnt[p] > CAP && (p & 3) == w && Tp == 0) {
      const float* zp = zb + (cc0 + (p >> 2)) * 1024 + (p & 3);
      float bd = 3.4e38f; int bi = 0x7FFFFFFF;
      for (int k = lane; k < 1024; k += 64) {
        const float* er = E + (size_t)k * 256;
        float dot = 0.0f;
        #pragma unroll 8
        for (int c = 0; c < 256; c++)
          dot = __fmaf_rn(zp[4 * c], er[c], dot);
        float d2 = __fsub_rn(__fadd_rn(se_g[k], szs[p]), __fmul_rn(2.0f, dot));
        if (d2 < bd || (d2 == bd && k < bi)) { bd = d2; bi = k; }
      }
      #pragma unroll
      for (int mm = 32; mm >= 1; mm >>= 1) {
        float d2 = __shfl_xor(bd, mm, 64);
        int i2 = __shfl_xor(bi, mm, 64);
        if (d2 < bd || (d2 == bd && i2 < bi)) { bd = d2; bi = i2; }
      }
      if (lane == 0) {
        int rr = p >> 2, w0 = p & 3;
        out[IDX_OFF + b * 1024 + (w0 * 256 + cc0 + rr)] = (float)bi;
      }
    }
  }
}

// ---------------------------------------------------------------------------
// kout: z_q_st = fl(zp + fl(zq - zp)); per-block loss partial -> d_ws
// ---------------------------------------------------------------------------
__global__ __launch_bounds__(256) void kout(const float* __restrict__ z,
                                            const float* __restrict__ E,
                                            float* __restrict__ out,
                                            float* __restrict__ ws) {
  __shared__ float red[4];
  const int t = threadIdx.x;
  const size_t g4 = (size_t)blockIdx.x * 256 + t;
  const size_t g = g4 * 4;
  const int b = (int)(g >> 18);
  const int c = (int)((g >> 10) & 255);
  const int n = (int)(g & 1023);

  float4 zp = *(const float4*)(z + g);
  float4 idxf = *(const float4*)(out + IDX_OFF + b * 1024 + n);
  int i0 = (int)idxf.x, i1 = (int)idxf.y, i2 = (int)idxf.z, i3 = (int)idxf.w;
  float q0 = E[i0 * 256 + c];
  float q1 = E[i1 * 256 + c];
  float q2 = E[i2 * 256 + c];
  float q3 = E[i3 * 256 + c];
  float d0 = __fsub_rn(q0, zp.x);
  float d1 = __fsub_rn(q1, zp.y);
  float d2 = __fsub_rn(q2, zp.z);
  float d3 = __fsub_rn(q3, zp.w);
  float4 o;
  o.x = __fadd_rn(zp.x, d0);
  o.y = __fadd_rn(zp.y, d1);
  o.z = __fadd_rn(zp.z, d2);
  o.w = __fadd_rn(zp.w, d3);
  *(float4*)(out + g) = o;

  float s = d0 * d0 + d1 * d1 + d2 * d2 + d3 * d3;
  #pragma unroll
  for (int off = 32; off > 0; off >>= 1) s += __shfl_down(s, off);
  if ((t & 63) == 0) red[t >> 6] = s;
  __syncthreads();
  if (t == 0) ws[blockIdx.x] = red[0] + red[1] + red[2] + red[3];
}

// ---------------------------------------------------------------------------
// kfin: loss = 1.25 * (sum(ws)/N)
// ---------------------------------------------------------------------------
__global__ __launch_bounds__(256) void kfin(const float* __restrict__ ws,
                                            float* __restrict__ out) {
  __shared__ float red[4];
  const int t = threadIdx.x;
  float s = 0.0f;
  #pragma unroll
  for (int i = 0; i < 32; i++) s += ws[t + 256 * i];
  #pragma unroll
  for (int off = 32; off > 0; off >>= 1) s += __shfl_down(s, off);
  if ((t & 63) == 0) red[t >> 6] = s;
  __syncthreads();
  if (t == 0) {
    float S = red[0] + red[1] + red[2] + red[3];
    float m = S / 8388608.0f;
    out[LOSS_OFF] = __fadd_rn(m, __fmul_rn(0.25f, m));
  }
}

extern "C" void kernel_launch(void* const* d_in, const int* in_sizes, int n_in,
                              void* d_out, int out_size, void* d_ws, size_t ws_size,
                              hipStream_t stream) {
  const float* z = (const float*)d_in[0];    // [32,256,32,32]
  const float* E = (const float*)d_in[1];    // [1024,256]
  float* out = (float*)d_out;
  float* ws = (float*)d_ws;

  ktr<<<dim3(16, 4), 256, 0, stream>>>(E, out);
  kse<<<dim3(4), 256, 0, stream>>>(out);
  kes<<<dim3(64), 256, 0, stream>>>(E, out);
  kzt<<<dim3(16, 32), 256, 0, stream>>>(z, out);
  kmain<<<dim3(16, 32), 512, 0, stream>>>(z, E, out);
  kout<<<dim3(8192), 256, 0, stream>>>(z, E, out, ws);
  kfin<<<dim3(1), 256, 0, stream>>>(ws, out);
}

// Round 11
// 283.396 us; speedup vs baseline: 1.0779x; 1.0779x over previous
//
#include <hip/hip_runtime.h>
#include <stdint.h>

// Problem constants
#define ZSIZE   8388608      // 32*256*32*32
#define NPIX    32768        // 32*32*32
#define IDX_OFF ZSIZE        // idx output offset (floats) in d_out
#define LOSS_OFF (ZSIZE + NPIX)
#define ET_OFF  1024         // Et fp32 [256][1024] scratch (for kse)
#define E1_OFF  263168       // e1s swizzled bf16 (131072 floats = 512 KB)
#define ZT_OFF  394240       // zt bf16 [32][1024][256] (4194304 floats)
#define SZ_OFF  4588544      // sz fp32 [32][1024] (32768 floats), after zt
#define CAP     24           // candidate slots per pixel
#define WWIN    6.0e-3f      // window >= 2*eps_bound (eps<=2.4e-3 rigorous)

using v8s = __attribute__((ext_vector_type(8))) short;   // 8 bf16 (4 VGPR)
using v4f = __attribute__((ext_vector_type(4))) float;   // MFMA acc

__device__ __forceinline__ unsigned short bf16rne(float f) {
  unsigned u = __float_as_uint(f);
  return (unsigned short)((u + 0x7FFFu + ((u >> 16) & 1u)) >> 16);
}

// async global->LDS, 16B per lane; per-wave, LDS dest = base + lane*16
// (contiguous in lane order — satisfied by all uses below).  Proven in R0.
typedef const __attribute__((address_space(1))) void gv_t;
typedef __attribute__((address_space(3))) void sv_t;
__device__ __forceinline__ void gl_lds16(const void* g, void* l) {
  __builtin_amdgcn_global_load_lds((gv_t*)g, (sv_t*)l, 16, 0, 0);
}

// ---------------------------------------------------------------------------
// ktr: transpose embedding E[1024][256] -> Et[256][1024] (feeds kse only)
// ---------------------------------------------------------------------------
__global__ __launch_bounds__(256) void ktr(const float* __restrict__ E,
                                           float* __restrict__ out) {
  __shared__ float tile[64][65];
  const int k0 = blockIdx.x * 64;
  const int c0 = blockIdx.y * 64;
  const int t = threadIdx.x;
  #pragma unroll
  for (int i = 0; i < 4; i++) {
    int f = t + 256 * i;
    int r = f >> 4, q = f & 15;
    float4 e = *(const float4*)(E + (k0 + r) * 256 + c0 + 4 * q);
    tile[r][4 * q + 0] = e.x; tile[r][4 * q + 1] = e.y;
    tile[r][4 * q + 2] = e.z; tile[r][4 * q + 3] = e.w;
  }
  __syncthreads();
  #pragma unroll
  for (int i = 0; i < 4; i++) {
    int f = t + 256 * i;
    int cr = f >> 4, kq = f & 15;
    float4 o;
    o.x = tile[4 * kq + 0][cr];
    o.y = tile[4 * kq + 1][cr];
    o.z = tile[4 * kq + 2][cr];
    o.w = tile[4 * kq + 3][cr];
    *(float4*)(out + ET_OFF + (c0 + cr) * 1024 + k0 + 4 * kq) = o;
  }
}

// ---------------------------------------------------------------------------
// kse: se[k] = ascending-c sequential fp32 chain of E[k][c]^2 (bit-faithful)
// ---------------------------------------------------------------------------
__global__ __launch_bounds__(256) void kse(float* __restrict__ out) {
  const int k = blockIdx.x * 256 + threadIdx.x;
  const float* Et = out + ET_OFF;
  float acc = 0.0f;
  #pragma unroll 8
  for (int c = 0; c < 256; c++) {
    float v = Et[c * 1024 + k];
    acc = __fadd_rn(acc, __fmul_rn(v, v));
  }
  out[k] = acc;
}

// ---------------------------------------------------------------------------
// kes: swizzled bf16 embedding in MFMA B-fragment order.
// e1s[tile][chunk=s*64+lane][8 shorts]: chunk holds
// bf16(E[16*tile + (lane&15)][8*((lane>>4)&3) + 32*s + 0..7]).
// A wave's B-load for (tile,s) is 64 lanes x 16B = 1KB contiguous.
// ---------------------------------------------------------------------------
__global__ __launch_bounds__(256) void kes(const float* __restrict__ E,
                                           float* __restrict__ out) {
  unsigned short* e1s = (unsigned short*)(out + E1_OFF);
  const int tile = blockIdx.x;       // 0..63
  const int t = threadIdx.x;
  #pragma unroll
  for (int i = 0; i < 2; i++) {
    int chunk = t + 256 * i;         // 0..511
    int s = chunk >> 6, lane = chunk & 63;
    int r = lane & 15, h = (lane >> 4) & 3;
    const float* src = E + (16 * tile + r) * 256 + 8 * h + 32 * s;
    unsigned short o[8];
    #pragma unroll
    for (int j = 0; j < 8; j++) o[j] = bf16rne(src[j]);
    *(uint4*)(e1s + (size_t)tile * 4096 + (size_t)chunk * 8) = *(const uint4*)o;
  }
}

// ---------------------------------------------------------------------------
// kzt: zt[b][n][c] = bf16_rne(zz[c][n]), n = w0*256 + m; also emits
// szg[b][n] = exact ascending-c fp32 chain of zz[c][n]^2 (bit-identical to
// the reference order).  Proven in R10.
// ---------------------------------------------------------------------------
__global__ __launch_bounds__(256) void kzt(const float* __restrict__ z,
                                           float* __restrict__ out) {
  __shared__ float tile[16][1028];   // 16 z-rows x 1024, pad 1028
  unsigned short* zt = (unsigned short*)(out + ZT_OFF);
  float* szg = out + SZ_OFF;
  const int mg = blockIdx.x;         // 0..15 (16-row group)
  const int b  = blockIdx.y;         // 0..31
  const int t = threadIdx.x;
  #pragma unroll
  for (int i = 0; i < 16; i++) {     // row m=i, q=t: coalesced float4 loads
    float4 v = *(const float4*)(z + (size_t)b * 262144 + (size_t)(mg * 16 + i) * 1024 + 4 * t);
    *(float4*)&tile[i][4 * t] = v;
  }
  __syncthreads();
  const int m = t & 15, w0 = (t >> 4) & 3;   // R = t&63 spans (m,w0)
  const int n = w0 * 256 + mg * 16 + m;
  #pragma unroll
  for (int i = 0; i < 8; i++) {
    int g = 4 * i + (t >> 6);        // 0..31: 8-channel group
    int c0 = 8 * g;
    unsigned short o[8];
    #pragma unroll
    for (int j = 0; j < 8; j++)
      o[j] = bf16rne(tile[m][4 * (c0 + j) + w0]);
    *(uint4*)(zt + ((size_t)(b * 1024 + n)) * 256 + c0) = *(const uint4*)o;
  }
  // ---- sz: exact sequential chain per pixel (64 threads; 2-way banks) ----
  if (t < 64) {
    const int ms = t >> 2, ws = t & 3;
    float a = 0.0f;
    #pragma unroll 8
    for (int c = 0; c < 256; c++) {
      float v = tile[ms][4 * c + ws];
      a = __fadd_rn(a, __fmul_rn(v, v));
    }
    szg[b * 1024 + ws * 256 + mg * 16 + ms] = a;
  }
}

// ---------------------------------------------------------------------------
// kmain: MFMA approximate distances + provably-sound exact rescreen.
// R11 change: R5/R9/R10 evidence says the K-loop is bound by per-ti L2
// round-trips (issue 8 loads -> wait ~300cy -> MFMA), and neither register
// dbuf (spills: R6/R7/R8) nor more waves (null: R10) fixes it.  Fix:
// WAVE-PRIVATE ASYNC LDS DOUBLE-BUFFER via global_load_lds (zero VGPR).
// Per ti: issue 8 gl_lds for tile ti+1 into buf^1; s_waitcnt vmcnt(8)
// (counted, never 0 mid-loop) guarantees buf ready; ds_read_b128 + MFMA
// from LDS (~12cy/read, contiguous = conflict-free).  No barriers in the
// K-loop (buffers wave-private; same-wave vmcnt retire => LDS visible).
// In-loop VMEM = staging only (se moved to LDS ses[1024]) so vmcnt
// counting is exact.  B bytes identical -> numerics unchanged (absmax=0
// proven R2-R10).  (256,1) removes the 128-VGPR cliff; LDS 79.6KB = 2
// blocks/CU (same residency as R5).  Canary: WRITE_SIZE ~128KB.
// ---------------------------------------------------------------------------
__global__ __launch_bounds__(256, 1) void kmain(const float* __restrict__ z,
                                                const float* __restrict__ E,
                                                float* __restrict__ out) {
  __shared__ __attribute__((aligned(16))) short bufB[4][2][4096];  // 64 KB
  __shared__ __attribute__((aligned(16))) float ses[1024];         // 4 KB
  __shared__ __attribute__((aligned(16))) float szs[64];
  __shared__ __attribute__((aligned(16))) float dmins[64];
  __shared__ unsigned short candK[64 * CAP];                       // 3 KB
  __shared__ float candD[64 * CAP];                                // 6 KB
  __shared__ int   cnt[64];

  const int t = threadIdx.x;
  const int ccg = blockIdx.x, b = blockIdx.y;
  const int cc0 = ccg * 16;
  const int lane = t & 63, w = t >> 6;   // wave index == code-tile phase
  const int r = t & 15, h = (t >> 4) & 3;
  const int w16r = w * 16 + r;
  const float* zb = z + (size_t)b * 262144;
  const float* se_g = out;
  const unsigned short* e1s = (const unsigned short*)(out + E1_OFF);
  const unsigned short* zt = (const unsigned short*)(out + ZT_OFF);
  const float* szg = out + SZ_OFF;

  if (t < 64) {
    cnt[t] = 0; dmins[t] = 3.4e38f;
    szs[t] = szg[b * 1024 + (t & 3) * 256 + cc0 + (t >> 2)];
  }
  *(float4*)&ses[4 * t] = *(const float4*)(se_g + 4 * t);   // coalesced
  __syncthreads();

  // stage tile TAU into this wave's buffer CUR (8 x 1KB async issues)
#define STAGE(TAU, CUR)                                                       \
  {                                                                           \
    const unsigned short* sp_ = e1s + (size_t)(TAU) * 4096 + lane * 8;        \
    short* dp_ = &bufB[w][CUR][lane * 8];                                     \
    _Pragma("unroll")                                                         \
    for (int s_ = 0; s_ < 8; s_++)                                            \
      gl_lds16((const void*)(sp_ + 512 * s_), (void*)(dp_ + 512 * s_));       \
  }

  // MFMA body for tile TI from buffer CUR (B values identical to R5's)
#define MBODY(TI, CUR)                                                        \
  {                                                                           \
    const short* bb_ = &bufB[w][CUR][lane * 8];                               \
    v4f acc0 = (v4f){0.f, 0.f, 0.f, 0.f};                                     \
    v4f acc1 = (v4f){0.f, 0.f, 0.f, 0.f};                                     \
    _Pragma("unroll")                                                         \
    for (int s_ = 0; s_ < 8; s_++) {                                          \
      v8s B_ = *(const v8s*)(bb_ + 512 * s_);                                 \
      acc0 = __builtin_amdgcn_mfma_f32_16x16x32_bf16(A0[s_], B_, acc0, 0, 0, 0); \
      acc1 = __builtin_amdgcn_mfma_f32_16x16x32_bf16(A1[s_], B_, acc1, 0, 0, 0); \
    }                                                                         \
    se_l = ses[(TI) * 64 + w16r];                                             \
    ACC0 = acc0; ACC1 = acc1;                                                 \
  }

  // ======== phase 1: min scan ========
  #pragma unroll 1
  for (int Tp = 0; Tp < 2; Tp++) {
    const int T0 = 2 * Tp, T1 = T0 + 1;
    v8s A0[8], A1[8];
    {
      const unsigned short* a0p =
          zt + ((size_t)(b * 1024 + T0 * 256 + cc0 + r)) * 256 + 8 * h;
      const unsigned short* a1p = a0p + 256 * 256;   // T1 = T0+1
      #pragma unroll
      for (int s = 0; s < 8; s++) {
        A0[s] = *(const v8s*)(a0p + 32 * s);
        A1[s] = *(const v8s*)(a1p + 32 * s);
      }
    }
    float sz0[4], sz1[4], b0[4], b1[4];
    #pragma unroll
    for (int reg = 0; reg < 4; reg++) {
      sz0[reg] = szs[16 * h + 4 * reg + T0];
      sz1[reg] = szs[16 * h + 4 * reg + T1];
      b0[reg] = 3.4e38f; b1[reg] = 3.4e38f;
    }

    int cur = 0;
    STAGE(w, 0);                     // tile for ti=0
    v4f ACC0, ACC1; float se_l;
    #pragma unroll 1
    for (int ti = 0; ti < 15; ti++) {
      STAGE(4 * (ti + 1) + w, cur ^ 1);
      asm volatile("s_waitcnt vmcnt(8)" ::: "memory");
      __builtin_amdgcn_sched_barrier(0);
      MBODY(ti, cur);
      #pragma unroll
      for (int reg = 0; reg < 4; reg++) {
        b0[reg] = fminf(b0[reg], (se_l + sz0[reg]) - 2.0f * ACC0[reg]);
        b1[reg] = fminf(b1[reg], (se_l + sz1[reg]) - 2.0f * ACC1[reg]);
      }
      cur ^= 1;
    }
    asm volatile("s_waitcnt vmcnt(0)" ::: "memory");
    __builtin_amdgcn_sched_barrier(0);
    MBODY(15, cur);
    #pragma unroll
    for (int reg = 0; reg < 4; reg++) {
      b0[reg] = fminf(b0[reg], (se_l + sz0[reg]) - 2.0f * ACC0[reg]);
      b1[reg] = fminf(b1[reg], (se_l + sz1[reg]) - 2.0f * ACC1[reg]);
    }
    #pragma unroll
    for (int reg = 0; reg < 4; reg++) {
      atomicMin((int*)&dmins[16 * h + 4 * reg + T0], __float_as_int(b0[reg]));
      atomicMin((int*)&dmins[16 * h + 4 * reg + T1], __float_as_int(b1[reg]));
    }
  }
  __syncthreads();   // dmins exact-final

  // ======== phase 2: recompute dd, append dd <= dmin + W ========
  #pragma unroll 1
  for (int Tp = 0; Tp < 2; Tp++) {
    const int T0 = 2 * Tp, T1 = T0 + 1;
    v8s A0[8], A1[8];
    {
      const unsigned short* a0p =
          zt + ((size_t)(b * 1024 + T0 * 256 + cc0 + r)) * 256 + 8 * h;
      const unsigned short* a1p = a0p + 256 * 256;
      #pragma unroll
      for (int s = 0; s < 8; s++) {
        A0[s] = *(const v8s*)(a0p + 32 * s);
        A1[s] = *(const v8s*)(a1p + 32 * s);
      }
    }
    float sz0[4], sz1[4], th0[4], th1[4];
    #pragma unroll
    for (int reg = 0; reg < 4; reg++) {
      sz0[reg] = szs[16 * h + 4 * reg + T0];
      sz1[reg] = szs[16 * h + 4 * reg + T1];
      th0[reg] = dmins[16 * h + 4 * reg + T0] + WWIN;
      th1[reg] = dmins[16 * h + 4 * reg + T1] + WWIN;
    }

    int cur = 0;
    STAGE(w, 0);
    v4f ACC0, ACC1; float se_l;
    #pragma unroll 1
    for (int ti = 0; ti < 16; ti++) {
      if (ti < 15) {
        STAGE(4 * (ti + 1) + w, cur ^ 1);
        asm volatile("s_waitcnt vmcnt(8)" ::: "memory");
      } else {
        asm volatile("s_waitcnt vmcnt(0)" ::: "memory");
      }
      __builtin_amdgcn_sched_barrier(0);
      MBODY(ti, cur);
      const int kl = ti * 64 + w16r;
      #pragma unroll
      for (int reg = 0; reg < 4; reg++) {
        float dd0 = (se_l + sz0[reg]) - 2.0f * ACC0[reg];
        if (dd0 <= th0[reg]) {
          int p = 16 * h + 4 * reg + T0;
          int o = atomicAdd(&cnt[p], 1);
          if (o < CAP) { candK[p * CAP + o] = (unsigned short)kl; candD[p * CAP + o] = dd0; }
        }
        float dd1 = (se_l + sz1[reg]) - 2.0f * ACC1[reg];
        if (dd1 <= th1[reg]) {
          int p = 16 * h + 4 * reg + T1;
          int o = atomicAdd(&cnt[p], 1);
          if (o < CAP) { candK[p * CAP + o] = (unsigned short)kl; candD[p * CAP + o] = dd1; }
        }
      }
      cur ^= 1;
    }
  }
#undef MBODY
#undef STAGE
  __syncthreads();   // all appends visible

  // ---- exact rescreen: bit-identical fp32 chain; z read from global ----
  for (int i = t; i < 64 * CAP; i += 256) {
    int p = i / CAP, slot = i - p * CAP;
    int cn = cnt[p];
    if (cn > CAP || slot >= cn) continue;     // overflow px -> fallback
    int k = candK[i];
    const float* er = E + (size_t)k * 256;
    const float* zp = zb + (cc0 + (p >> 2)) * 1024 + (p & 3);
    float dot = 0.0f;
    #pragma unroll 8
    for (int c = 0; c < 256; c++)
      dot = __fmaf_rn(zp[4 * c], er[c], dot);
    candD[i] = __fsub_rn(__fadd_rn(se_g[k], szs[p]), __fmul_rn(2.0f, dot));
  }
  __syncthreads();

  // ---- winners: lexicographic (d,k) min == first-index argmin ----
  if (t < 64) {
    int p = t, cn = cnt[p];
    if (cn <= CAP) {
      float bd = 3.4e38f; int bi = 0x7FFFFFFF;
      for (int s2 = 0; s2 < cn; s2++) {
        float d2 = candD[p * CAP + s2]; int k2 = candK[p * CAP + s2];
        if (d2 < bd || (d2 == bd && k2 < bi)) { bd = d2; bi = k2; }
      }
      int rr = p >> 2, w0 = p & 3;
      out[IDX_OFF + b * 1024 + (w0 * 256 + cc0 + rr)] = (float)bi;
    }
  }

  // ---- fallback: overflowed px -> exact full scan by one wave (dead code
  // in practice: exact-final threshold, lambda ~ 3/px, P(>24) ~ 1e-12) ----
  for (int p = 0; p < 64; p++) {
    if (cnt[p] > CAP && (p & 3) == w) {
      const float* zp = zb + (cc0 + (p >> 2)) * 1024 + (p & 3);
      float bd = 3.4e38f; int bi = 0x7FFFFFFF;
      for (int k = lane; k < 1024; k += 64) {
        const float* er = E + (size_t)k * 256;
        float dot = 0.0f;
        #pragma unroll 8
        for (int c = 0; c < 256; c++)
          dot = __fmaf_rn(zp[4 * c], er[c], dot);
        float d2 = __fsub_rn(__fadd_rn(se_g[k], szs[p]), __fmul_rn(2.0f, dot));
        if (d2 < bd || (d2 == bd && k < bi)) { bd = d2; bi = k; }
      }
      #pragma unroll
      for (int mm = 32; mm >= 1; mm >>= 1) {
        float d2 = __shfl_xor(bd, mm, 64);
        int i2 = __shfl_xor(bi, mm, 64);
        if (d2 < bd || (d2 == bd && i2 < bi)) { bd = d2; bi = i2; }
      }
      if (lane == 0) {
        int rr = p >> 2, w0 = p & 3;
        out[IDX_OFF + b * 1024 + (w0 * 256 + cc0 + rr)] = (float)bi;
      }
    }
  }
}

// ---------------------------------------------------------------------------
// kout: z_q_st = fl(zp + fl(zq - zp)); per-block loss partial -> d_ws
// ---------------------------------------------------------------------------
__global__ __launch_bounds__(256) void kout(const float* __restrict__ z,
                                            const float* __restrict__ E,
                                            float* __restrict__ out,
                                            float* __restrict__ ws) {
  __shared__ float red[4];
  const int t = threadIdx.x;
  const size_t g4 = (size_t)blockIdx.x * 256 + t;
  const size_t g = g4 * 4;
  const int b = (int)(g >> 18);
  const int c = (int)((g >> 10) & 255);
  const int n = (int)(g & 1023);

  float4 zp = *(const float4*)(z + g);
  float4 idxf = *(const float4*)(out + IDX_OFF + b * 1024 + n);
  int i0 = (int)idxf.x, i1 = (int)idxf.y, i2 = (int)idxf.z, i3 = (int)idxf.w;
  float q0 = E[i0 * 256 + c];
  float q1 = E[i1 * 256 + c];
  float q2 = E[i2 * 256 + c];
  float q3 = E[i3 * 256 + c];
  float d0 = __fsub_rn(q0, zp.x);
  float d1 = __fsub_rn(q1, zp.y);
  float d2 = __fsub_rn(q2, zp.z);
  float d3 = __fsub_rn(q3, zp.w);
  float4 o;
  o.x = __fadd_rn(zp.x, d0);
  o.y = __fadd_rn(zp.y, d1);
  o.z = __fadd_rn(zp.z, d2);
  o.w = __fadd_rn(zp.w, d3);
  *(float4*)(out + g) = o;

  float s = d0 * d0 + d1 * d1 + d2 * d2 + d3 * d3;
  #pragma unroll
  for (int off = 32; off > 0; off >>= 1) s += __shfl_down(s, off);
  if ((t & 63) == 0) red[t >> 6] = s;
  __syncthreads();
  if (t == 0) ws[blockIdx.x] = red[0] + red[1] + red[2] + red[3];
}

// ---------------------------------------------------------------------------
// kfin: loss = 1.25 * (sum(ws)/N)
// ---------------------------------------------------------------------------
__global__ __launch_bounds__(256) void kfin(const float* __restrict__ ws,
                                            float* __restrict__ out) {
  __shared__ float red[4];
  const int t = threadIdx.x;
  float s = 0.0f;
  #pragma unroll
  for (int i = 0; i < 32; i++) s += ws[t + 256 * i];
  #pragma unroll
  for (int off = 32; off > 0; off >>= 1) s += __shfl_down(s, off);
  if ((t & 63) == 0) red[t >> 6] = s;
  __syncthreads();
  if (t == 0) {
    float S = red[0] + red[1] + red[2] + red[3];
    float m = S / 8388608.0f;
    out[LOSS_OFF] = __fadd_rn(m, __fmul_rn(0.25f, m));
  }
}

extern "C" void kernel_launch(void* const* d_in, const int* in_sizes, int n_in,
                              void* d_out, int out_size, void* d_ws, size_t ws_size,
                              hipStream_t stream) {
  const float* z = (const float*)d_in[0];    // [32,256,32,32]
  const float* E = (const float*)d_in[1];    // [1024,256]
  float* out = (float*)d_out;
  float* ws = (float*)d_ws;

  ktr<<<dim3(16, 4), 256, 0, stream>>>(E, out);
  kse<<<dim3(4), 256, 0, stream>>>(out);
  kes<<<dim3(64), 256, 0, stream>>>(E, out);
  kzt<<<dim3(16, 32), 256, 0, stream>>>(z, out);
  kmain<<<dim3(16, 32), 256, 0, stream>>>(z, E, out);
  kout<<<dim3(8192), 256, 0, stream>>>(z, E, out, ws);
  kfin<<<dim3(1), 256, 0, stream>>>(ws, out);
}

// Round 13
// 261.980 us; speedup vs baseline: 1.1660x; 1.0817x over previous
//
#include <hip/hip_runtime.h>
#include <stdint.h>

// Problem constants
#define ZSIZE   8388608      // 32*256*32*32
#define NPIX    32768        // 32*32*32
#define IDX_OFF ZSIZE        // idx output offset (floats) in d_out
#define LOSS_OFF (ZSIZE + NPIX)
#define ET_OFF  1024         // Et fp32 [256][1024] scratch (for kse)
#define E1_OFF  263168       // e1s swizzled bf16 (131072 floats = 512 KB)
#define ZT_OFF  394240       // zt bf16 [32][1024][256] (4194304 floats)
#define SZ_OFF  4588544      // sz fp32 [32][1024] (32768 floats), after zt
#define CAP     24           // candidate slots per pixel
#define WWIN    6.0e-3f      // window >= 2*eps_bound (eps<=2.4e-3 rigorous)
#define QMARG   1.5e-4f      // quantization compare margin (res 3.05e-5)

using v8s = __attribute__((ext_vector_type(8))) short;   // 8 bf16 (4 VGPR)
using v4f = __attribute__((ext_vector_type(4))) float;   // MFMA acc

__device__ __forceinline__ unsigned short bf16rne(float f) {
  unsigned u = __float_as_uint(f);
  return (unsigned short)((u + 0x7FFFu + ((u >> 16) & 1u)) >> 16);
}

// ---------------------------------------------------------------------------
// ktr: transpose embedding E[1024][256] -> Et[256][1024] (feeds kse only)
// ---------------------------------------------------------------------------
__global__ __launch_bounds__(256) void ktr(const float* __restrict__ E,
                                           float* __restrict__ out) {
  __shared__ float tile[64][65];
  const int k0 = blockIdx.x * 64;
  const int c0 = blockIdx.y * 64;
  const int t = threadIdx.x;
  #pragma unroll
  for (int i = 0; i < 4; i++) {
    int f = t + 256 * i;
    int r = f >> 4, q = f & 15;
    float4 e = *(const float4*)(E + (k0 + r) * 256 + c0 + 4 * q);
    tile[r][4 * q + 0] = e.x; tile[r][4 * q + 1] = e.y;
    tile[r][4 * q + 2] = e.z; tile[r][4 * q + 3] = e.w;
  }
  __syncthreads();
  #pragma unroll
  for (int i = 0; i < 4; i++) {
    int f = t + 256 * i;
    int cr = f >> 4, kq = f & 15;
    float4 o;
    o.x = tile[4 * kq + 0][cr];
    o.y = tile[4 * kq + 1][cr];
    o.z = tile[4 * kq + 2][cr];
    o.w = tile[4 * kq + 3][cr];
    *(float4*)(out + ET_OFF + (c0 + cr) * 1024 + k0 + 4 * kq) = o;
  }
}

// ---------------------------------------------------------------------------
// kse: se[k] = ascending-c sequential fp32 chain of E[k][c]^2 (bit-faithful)
// ---------------------------------------------------------------------------
__global__ __launch_bounds__(256) void kse(float* __restrict__ out) {
  const int k = blockIdx.x * 256 + threadIdx.x;
  const float* Et = out + ET_OFF;
  float acc = 0.0f;
  #pragma unroll 8
  for (int c = 0; c < 256; c++) {
    float v = Et[c * 1024 + k];
    acc = __fadd_rn(acc, __fmul_rn(v, v));
  }
  out[k] = acc;
}

// ---------------------------------------------------------------------------
// kes: swizzled bf16 embedding in MFMA B-fragment order.
// e1s[tile][chunk=s*64+lane][8 shorts]: chunk holds
// bf16(E[16*tile + (lane&15)][8*((lane>>4)&3) + 32*s + 0..7]).
// A wave's B-load for (tile,s) is 64 lanes x 16B = 1KB contiguous.
// ---------------------------------------------------------------------------
__global__ __launch_bounds__(256) void kes(const float* __restrict__ E,
                                           float* __restrict__ out) {
  unsigned short* e1s = (unsigned short*)(out + E1_OFF);
  const int tile = blockIdx.x;       // 0..63
  const int t = threadIdx.x;
  #pragma unroll
  for (int i = 0; i < 2; i++) {
    int chunk = t + 256 * i;         // 0..511
    int s = chunk >> 6, lane = chunk & 63;
    int r = lane & 15, h = (lane >> 4) & 3;
    const float* src = E + (16 * tile + r) * 256 + 8 * h + 32 * s;
    unsigned short o[8];
    #pragma unroll
    for (int j = 0; j < 8; j++) o[j] = bf16rne(src[j]);
    *(uint4*)(e1s + (size_t)tile * 4096 + (size_t)chunk * 8) = *(const uint4*)o;
  }
}

// ---------------------------------------------------------------------------
// kzt: zt[b][n][c] = bf16_rne(zz[c][n]), n = w0*256 + m; also emits
// szg[b][n] = exact ascending-c fp32 chain of zz[c][n]^2 (bit-identical to
// the reference order).  Proven in R10.
// ---------------------------------------------------------------------------
__global__ __launch_bounds__(256) void kzt(const float* __restrict__ z,
                                           float* __restrict__ out) {
  __shared__ float tile[16][1028];   // 16 z-rows x 1024, pad 1028
  unsigned short* zt = (unsigned short*)(out + ZT_OFF);
  float* szg = out + SZ_OFF;
  const int mg = blockIdx.x;         // 0..15 (16-row group)
  const int b  = blockIdx.y;         // 0..31
  const int t = threadIdx.x;
  #pragma unroll
  for (int i = 0; i < 16; i++) {     // row m=i, q=t: coalesced float4 loads
    float4 v = *(const float4*)(z + (size_t)b * 262144 + (size_t)(mg * 16 + i) * 1024 + 4 * t);
    *(float4*)&tile[i][4 * t] = v;
  }
  __syncthreads();
  const int m = t & 15, w0 = (t >> 4) & 3;   // R = t&63 spans (m,w0)
  const int n = w0 * 256 + mg * 16 + m;
  #pragma unroll
  for (int i = 0; i < 8; i++) {
    int g = 4 * i + (t >> 6);        // 0..31: 8-channel group
    int c0 = 8 * g;
    unsigned short o[8];
    #pragma unroll
    for (int j = 0; j < 8; j++)
      o[j] = bf16rne(tile[m][4 * (c0 + j) + w0]);
    *(uint4*)(zt + ((size_t)(b * 1024 + n)) * 256 + c0) = *(const uint4*)o;
  }
  // ---- sz: exact sequential chain per pixel (64 threads; 2-way banks) ----
  if (t < 64) {
    const int ms = t >> 2, ws = t & 3;
    float a = 0.0f;
    #pragma unroll 8
    for (int c = 0; c < 256; c++) {
      float v = tile[ms][4 * c + ws];
      a = __fadd_rn(a, __fmul_rn(v, v));
    }
    szg[b * 1024 + ws * 256 + mg * 16 + ms] = a;
  }
}

// ---------------------------------------------------------------------------
// kmain: MFMA approximate distances + provably-sound exact rescreen.
// R13 = R12 resubmission (R12 bench was an infra failure, kernel never ran)
// + one extra end-of-pass barrier for belt-and-braces.
// Rationale: every prior structure sweeps e1s 4x per wave (2 phases x 2
// T-pairs) — the real cost (L2-BW + hotspot; dbuf attempts all failed).
// Phase 2's GEMM exists only because 128 fp32 dd/thread spill — but the
// appended candD value is NEVER read (rescreen overwrites every valid
// slot), so phase 2 only needs the COMPARE.  dd - sz = se - 2*dot lies in
// [-0.65, 0.65] (||z||<=19, ||e||<=0.016) -> u16 fixed point (res 3.05e-5,
// trunc => f' <= f so window inclusion is automatic; margin 1.5e-4 added
// anyway; W - 2eps = 1.2e-3 >> margin).  fl(dd - sz) is exact (Sterbenz,
// dd ~ sz).  128 x u16 per thread = 64KB LDS (padded [256][65] u32,
// conflict-free) -> phase 2 becomes an LDS REPLAY: e1s traffic and MFMA
// both HALVE.  Min stays exact in registers -> dmins exact; soundness
// unchanged.  Extras filtered by exact rescreen.  Plus per-block
// ti-stagger (tj=(ti+perm)&15; min and set-membership order-independent)
// to decorrelate the lockstep e1s sweep across blocks (L2 channels).
// Canaries: VGPR ~95-110 (NOT 128), WRITE_SIZE ~128KB.
// ---------------------------------------------------------------------------
__global__ __launch_bounds__(256, 2) void kmain(const float* __restrict__ z,
                                                const float* __restrict__ E,
                                                float* __restrict__ out) {
  __shared__ __attribute__((aligned(16))) unsigned ddq[256][65];  // 66.5 KB
  __shared__ __attribute__((aligned(16))) float szs[64];
  __shared__ __attribute__((aligned(16))) float dmins[64];
  __shared__ unsigned short candK[64 * CAP];                      // 3 KB
  __shared__ float candD[64 * CAP];                               // 6 KB
  __shared__ int   cnt[64];

  const int t = threadIdx.x;
  const int ccg = blockIdx.x, b = blockIdx.y;
  const int cc0 = ccg * 16;
  const int lane = t & 63, w = t >> 6;
  const int r = t & 15, h = (t >> 4) & 3;
  const int w16r = w * 16 + r;
  const int perm = (ccg + 2 * b) & 15;   // per-block ti stagger
  const float* zb = z + (size_t)b * 262144;
  const float* se_g = out;
  const unsigned short* e1s = (const unsigned short*)(out + E1_OFF);
  const unsigned short* zt = (const unsigned short*)(out + ZT_OFF);
  const float* szg = out + SZ_OFF;

  if (t < 64) {
    cnt[t] = 0; dmins[t] = 3.4e38f;
    szs[t] = szg[b * 1024 + (t & 3) * 256 + cc0 + (t >> 2)];
  }
  __syncthreads();

  #pragma unroll 1
  for (int Tp = 0; Tp < 2; Tp++) {
    const int T0 = 2 * Tp, T1 = T0 + 1;
    // ---- A-frags (T-pair shares every streamed B fragment) ----
    v8s A0[8], A1[8];
    {
      const unsigned short* a0p =
          zt + ((size_t)(b * 1024 + T0 * 256 + cc0 + r)) * 256 + 8 * h;
      const unsigned short* a1p = a0p + 256 * 256;   // T1 = T0+1
      #pragma unroll
      for (int s = 0; s < 8; s++) {
        A0[s] = *(const v8s*)(a0p + 32 * s);
        A1[s] = *(const v8s*)(a1p + 32 * s);
      }
    }
    float sz0[4], sz1[4], b0[4], b1[4];
    #pragma unroll
    for (int reg = 0; reg < 4; reg++) {
      sz0[reg] = szs[16 * h + 4 * reg + T0];
      sz1[reg] = szs[16 * h + 4 * reg + T1];
      b0[reg] = 3.4e38f; b1[reg] = 3.4e38f;
    }

    // ---- single GEMM sweep: exact min in regs + quantized dd to LDS ----
    #pragma unroll 4
    for (int ti = 0; ti < 16; ti++) {
      const int tj = (ti + perm) & 15;
      const unsigned short* bb = e1s + (size_t)(4 * tj + w) * 4096 + (size_t)lane * 8;
      v4f acc0 = (v4f){0.f, 0.f, 0.f, 0.f};
      v4f acc1 = (v4f){0.f, 0.f, 0.f, 0.f};
      #pragma unroll
      for (int s = 0; s < 8; s++) {
        v8s B_ = *(const v8s*)(bb + 512 * s);
        acc0 = __builtin_amdgcn_mfma_f32_16x16x32_bf16(A0[s], B_, acc0, 0, 0, 0);
        acc1 = __builtin_amdgcn_mfma_f32_16x16x32_bf16(A1[s], B_, acc1, 0, 0, 0);
      }
      float se_l = se_g[tj * 64 + w16r];
      #pragma unroll
      for (int reg = 0; reg < 4; reg++) {
        float dd0 = (se_l + sz0[reg]) - 2.0f * acc0[reg];
        float dd1 = (se_l + sz1[reg]) - 2.0f * acc1[reg];
        b0[reg] = fminf(b0[reg], dd0);
        b1[reg] = fminf(b1[reg], dd1);
        // f = dd - sz exact (Sterbenz); q = trunc((f+1)*32768), clamped
        float f0 = dd0 - sz0[reg], f1 = dd1 - sz1[reg];
        int q0 = (int)((f0 + 1.0f) * 32768.0f);
        int q1 = (int)((f1 + 1.0f) * 32768.0f);
        q0 = q0 < 0 ? 0 : (q0 > 65535 ? 65535 : q0);
        q1 = q1 < 0 ? 0 : (q1 > 65535 ? 65535 : q1);
        ddq[t][4 * ti + reg] = (unsigned)q0 | ((unsigned)q1 << 16);
      }
    }

    #pragma unroll
    for (int reg = 0; reg < 4; reg++) {
      atomicMin((int*)&dmins[16 * h + 4 * reg + T0], __float_as_int(b0[reg]));
      atomicMin((int*)&dmins[16 * h + 4 * reg + T1], __float_as_int(b1[reg]));
    }
    __syncthreads();   // dmins exact-final for this Tp's pixels

    // ---- replay from LDS: append q-decoded f <= (thr - sz) + margin ----
    float th0[4], th1[4];
    #pragma unroll
    for (int reg = 0; reg < 4; reg++) {
      th0[reg] = (dmins[16 * h + 4 * reg + T0] + WWIN) - sz0[reg] + QMARG;
      th1[reg] = (dmins[16 * h + 4 * reg + T1] + WWIN) - sz1[reg] + QMARG;
    }
    #pragma unroll 4
    for (int ti = 0; ti < 16; ti++) {
      const int kl = ((ti + perm) & 15) * 64 + w16r;
      #pragma unroll
      for (int reg = 0; reg < 4; reg++) {
        unsigned qd = ddq[t][4 * ti + reg];
        float f0 = (float)(qd & 0xFFFFu) * (1.0f / 32768.0f) - 1.0f;
        float f1 = (float)(qd >> 16) * (1.0f / 32768.0f) - 1.0f;
        if (f0 <= th0[reg]) {
          int p = 16 * h + 4 * reg + T0;
          int o = atomicAdd(&cnt[p], 1);
          if (o < CAP) candK[p * CAP + o] = (unsigned short)kl;
        }
        if (f1 <= th1[reg]) {
          int p = 16 * h + 4 * reg + T1;
          int o = atomicAdd(&cnt[p], 1);
          if (o < CAP) candK[p * CAP + o] = (unsigned short)kl;
        }
      }
    }
    __syncthreads();   // pass fully drained before next Tp reuses ddq
  }

  // ---- exact rescreen: bit-identical fp32 chain; overwrites every slot ----
  for (int i = t; i < 64 * CAP; i += 256) {
    int p = i / CAP, slot = i - p * CAP;
    int cn = cnt[p];
    if (cn > CAP || slot >= cn) continue;     // overflow px -> fallback
    int k = candK[i];
    const float* er = E + (size_t)k * 256;
    const float* zp = zb + (cc0 + (p >> 2)) * 1024 + (p & 3);
    float dot = 0.0f;
    #pragma unroll 8
    for (int c = 0; c < 256; c++)
      dot = __fmaf_rn(zp[4 * c], er[c], dot);
    candD[i] = __fsub_rn(__fadd_rn(se_g[k], szs[p]), __fmul_rn(2.0f, dot));
  }
  __syncthreads();

  // ---- winners: lexicographic (d,k) min == first-index argmin ----
  if (t < 64) {
    int p = t, cn = cnt[p];
    if (cn <= CAP) {
      float bd = 3.4e38f; int bi = 0x7FFFFFFF;
      for (int s2 = 0; s2 < cn; s2++) {
        float d2 = candD[p * CAP + s2]; int k2 = candK[p * CAP + s2];
        if (d2 < bd || (d2 == bd && k2 < bi)) { bd = d2; bi = k2; }
      }
      int rr = p >> 2, w0 = p & 3;
      out[IDX_OFF + b * 1024 + (w0 * 256 + cc0 + rr)] = (float)bi;
    }
  }

  // ---- fallback: overflowed px -> exact full scan by one wave (dead code
  // in practice: exact-final threshold, lambda ~ 2/px, P(>24) ~ 0) ----
  for (int p = 0; p < 64; p++) {
    if (cnt[p] > CAP && (p & 3) == w) {
      const float* zp = zb + (cc0 + (p >> 2)) * 1024 + (p & 3);
      float bd = 3.4e38f; int bi = 0x7FFFFFFF;
      for (int k = lane; k < 1024; k += 64) {
        const float* er = E + (size_t)k * 256;
        float dot = 0.0f;
        #pragma unroll 8
        for (int c = 0; c < 256; c++)
          dot = __fmaf_rn(zp[4 * c], er[c], dot);
        float d2 = __fsub_rn(__fadd_rn(se_g[k], szs[p]), __fmul_rn(2.0f, dot));
        if (d2 < bd || (d2 == bd && k < bi)) { bd = d2; bi = k; }
      }
      #pragma unroll
      for (int mm = 32; mm >= 1; mm >>= 1) {
        float d2 = __shfl_xor(bd, mm, 64);
        int i2 = __shfl_xor(bi, mm, 64);
        if (d2 < bd || (d2 == bd && i2 < bi)) { bd = d2; bi = i2; }
      }
      if (lane == 0) {
        int rr = p >> 2, w0 = p & 3;
        out[IDX_OFF + b * 1024 + (w0 * 256 + cc0 + rr)] = (float)bi;
      }
    }
  }
}

// ---------------------------------------------------------------------------
// kout: z_q_st = fl(zp + fl(zq - zp)); per-block loss partial -> d_ws
// ---------------------------------------------------------------------------
__global__ __launch_bounds__(256) void kout(const float* __restrict__ z,
                                            const float* __restrict__ E,
                                            float* __restrict__ out,
                                            float* __restrict__ ws) {
  __shared__ float red[4];
  const int t = threadIdx.x;
  const size_t g4 = (size_t)blockIdx.x * 256 + t;
  const size_t g = g4 * 4;
  const int b = (int)(g >> 18);
  const int c = (int)((g >> 10) & 255);
  const int n = (int)(g & 1023);

  float4 zp = *(const float4*)(z + g);
  float4 idxf = *(const float4*)(out + IDX_OFF + b * 1024 + n);
  int i0 = (int)idxf.x, i1 = (int)idxf.y, i2 = (int)idxf.z, i3 = (int)idxf.w;
  float q0 = E[i0 * 256 + c];
  float q1 = E[i1 * 256 + c];
  float q2 = E[i2 * 256 + c];
  float q3 = E[i3 * 256 + c];
  float d0 = __fsub_rn(q0, zp.x);
  float d1 = __fsub_rn(q1, zp.y);
  float d2 = __fsub_rn(q2, zp.z);
  float d3 = __fsub_rn(q3, zp.w);
  float4 o;
  o.x = __fadd_rn(zp.x, d0);
  o.y = __fadd_rn(zp.y, d1);
  o.z = __fadd_rn(zp.z, d2);
  o.w = __fadd_rn(zp.w, d3);
  *(float4*)(out + g) = o;

  float s = d0 * d0 + d1 * d1 + d2 * d2 + d3 * d3;
  #pragma unroll
  for (int off = 32; off > 0; off >>= 1) s += __shfl_down(s, off);
  if ((t & 63) == 0) red[t >> 6] = s;
  __syncthreads();
  if (t == 0) ws[blockIdx.x] = red[0] + red[1] + red[2] + red[3];
}

// ---------------------------------------------------------------------------
// kfin: loss = 1.25 * (sum(ws)/N)
// ---------------------------------------------------------------------------
__global__ __launch_bounds__(256) void kfin(const float* __restrict__ ws,
                                            float* __restrict__ out) {
  __shared__ float red[4];
  const int t = threadIdx.x;
  float s = 0.0f;
  #pragma unroll
  for (int i = 0; i < 32; i++) s += ws[t + 256 * i];
  #pragma unroll
  for (int off = 32; off > 0; off >>= 1) s += __shfl_down(s, off);
  if ((t & 63) == 0) red[t >> 6] = s;
  __syncthreads();
  if (t == 0) {
    float S = red[0] + red[1] + red[2] + red[3];
    float m = S / 8388608.0f;
    out[LOSS_OFF] = __fadd_rn(m, __fmul_rn(0.25f, m));
  }
}

extern "C" void kernel_launch(void* const* d_in, const int* in_sizes, int n_in,
                              void* d_out, int out_size, void* d_ws, size_t ws_size,
                              hipStream_t stream) {
  const float* z = (const float*)d_in[0];    // [32,256,32,32]
  const float* E = (const float*)d_in[1];    // [1024,256]
  float* out = (float*)d_out;
  float* ws = (float*)d_ws;

  ktr<<<dim3(16, 4), 256, 0, stream>>>(E, out);
  kse<<<dim3(4), 256, 0, stream>>>(out);
  kes<<<dim3(64), 256, 0, stream>>>(E, out);
  kzt<<<dim3(16, 32), 256, 0, stream>>>(z, out);
  kmain<<<dim3(16, 32), 256, 0, stream>>>(z, E, out);
  kout<<<dim3(8192), 256, 0, stream>>>(z, E, out, ws);
  kfin<<<dim3(1), 256, 0, stream>>>(ws, out);
}